// Round 1
// baseline (6272.845 us; speedup 1.0000x reference)
//
#include <hip/hip_runtime.h>
#include <math.h>

// DRC: x_G -> static gain curve -> x_L -> branching one-pole smoother -> gain.
// Phase 2 (smoother) is sequential per batch; B=16 chains of N=524288 steps.
// Branch removal: when aA<=aR the chosen branch == max of the two candidates;
// when aA>aR it's min, folded into max by sign flip s=-1 (z = s*y).

#define SRATE 44100.0f
#define TILE_V4 512   // float4 groups per LDS tile = 2048 samples

static __device__ __forceinline__ float san(float p){
    p = isnan(p) ? 0.0f : p;
    p = (p == 0.0f) ? 1e-10f : p;
    return p;
}

struct BatchParams { float thr, ratio, knee, aA, aR, s, mk; };

static __device__ __forceinline__ BatchParams load_params(const float* __restrict__ P, int b){
    float p0 = san(P[b*6+0]);
    float p1 = san(P[b*6+1]);
    float p2 = san(P[b*6+2]);
    float p3 = san(P[b*6+3]);
    float p4 = san(P[b*6+4]);
    float p5 = san(P[b*6+5]);
    BatchParams bp;
    bp.thr   = -p0 * 60.0f;
    bp.ratio =  p1 * 10.0f;
    float atk = fmaxf(p2 / 10.0f, 1e-4f);
    float rel = fmaxf(p3 * 3.0f, 0.005f);
    bp.knee  = p4 * 24.0f;
    const float LOG9 = 2.1972245773362196f;
    bp.aA = expf(-LOG9 / (SRATE * atk));
    bp.aR = expf(-LOG9 / (SRATE * rel));
    bp.s  = (bp.aA <= bp.aR) ? 1.0f : -1.0f;
    bp.mk = exp2f((p5 * 20.0f) * 0.16609640474436813f);  // 10^(mk_dB/20)
    return bp;
}

static __device__ __forceinline__ float compute_xl(float xin, float thr, float invr,
                                                   float knee, float i2k){
    float ax = fabsf(xin) + 1e-8f;
    float xg = fmaxf(20.0f * log10f(ax), -96.0f);
    float d  = xg - thr;
    float t2 = d + d;
    float u  = (d + knee) * 0.5f;
    float yk = xg + (invr * (u * u)) * i2k;     // knee region
    float ya = thr + d * invr;                  // above
    float yg = (t2 < -knee) ? xg : ((t2 > knee) ? ya : yk);
    return xg - yg;
}

// Pre-pass: compute x_L; if TWO, store s*(1-aA)*xl into outA and s*(1-aR)*xl
// into outR so the scan's inner loop is fma+fma+max only. Else store xl.
template<int TWO>
__global__ __launch_bounds__(256) void drc_pre(const float* __restrict__ x, const float* __restrict__ P,
                        float* __restrict__ outA, float* __restrict__ outR,
                        int nvpb, int total_vec){
    int stride = gridDim.x * blockDim.x;
    for (int v = blockIdx.x * blockDim.x + threadIdx.x; v < total_vec; v += stride){
        int b = v / nvpb;
        BatchParams bp = load_params(P, b);
        float invr = 1.0f / bp.ratio;
        float i2k  = 1.0f / (2.0f * bp.knee);
        float kAs = bp.s * (1.0f - bp.aA);
        float kRs = bp.s * (1.0f - bp.aR);
        float4 xv = reinterpret_cast<const float4*>(x)[v];
        float4 xl;
        xl.x = compute_xl(xv.x, bp.thr, invr, bp.knee, i2k);
        xl.y = compute_xl(xv.y, bp.thr, invr, bp.knee, i2k);
        xl.z = compute_xl(xv.z, bp.thr, invr, bp.knee, i2k);
        xl.w = compute_xl(xv.w, bp.thr, invr, bp.knee, i2k);
        if (TWO){
            float4 ca = { kAs*xl.x, kAs*xl.y, kAs*xl.z, kAs*xl.w };
            float4 cr = { kRs*xl.x, kRs*xl.y, kRs*xl.z, kRs*xl.w };
            reinterpret_cast<float4*>(outA)[v] = ca;
            reinterpret_cast<float4*>(outR)[v] = cr;
        } else {
            reinterpret_cast<float4*>(outA)[v] = xl;
        }
    }
}

// Sequential scan. One block per batch. Lane 0 of wave 0 runs the recurrence
// from LDS; waves 1..4 double-buffer-stage the next tile from global so the
// scan lane never waits on HBM latency. Writes z = s*y_L in place over bufA.
template<int TWO>
__global__ __launch_bounds__(320) void drc_scan(float* __restrict__ bufA, const float* __restrict__ bufR,
                         const float* __restrict__ P, int nvpb){
    const int b = blockIdx.x;
    BatchParams bp = load_params(P, b);
    const float aA = bp.aA, aR = bp.aR;
    const float kAs = bp.s * (1.0f - aA);
    const float kRs = bp.s * (1.0f - aR);

    __shared__ float4 sA[2][TILE_V4];
    __shared__ float4 sR[2][TILE_V4];

    const float4* gA = reinterpret_cast<const float4*>(bufA) + (size_t)b * nvpb;
    const float4* gR = TWO ? (reinterpret_cast<const float4*>(bufR) + (size_t)b * nvpb) : nullptr;
    float4*       gZ = reinterpret_cast<float4*>(bufA) + (size_t)b * nvpb;

    const int tid = threadIdx.x;
    const int nt  = nvpb / TILE_V4;

    auto stage = [&](int t, int buf){
        if (tid >= 64){
            int i0 = tid - 64;  // 0..255
            const float4* srcA = gA + t * TILE_V4;
            #pragma unroll
            for (int i = 0; i < TILE_V4; i += 256)
                sA[buf][i + i0] = srcA[i + i0];
            if (TWO){
                const float4* srcR = gR + t * TILE_V4;
                #pragma unroll
                for (int i = 0; i < TILE_V4; i += 256)
                    sR[buf][i + i0] = srcR[i + i0];
            }
        }
    };

    stage(0, 0);
    __syncthreads();

    float z = 0.0f;
    auto step = [&](float va, float vr){
        float ca, cr;
        if (TWO){ ca = va; cr = vr; }
        else    { ca = kAs * va; cr = kRs * va; }
        z = fmaxf(fmaf(aA, z, ca), fmaf(aR, z, cr));
    };

    for (int t = 0; t < nt; ++t){
        const int cur = t & 1;
        if (t + 1 < nt) stage(t + 1, cur ^ 1);
        if (tid == 0){
            float4* zt = gZ + t * TILE_V4;
            int g0 = 0;
            if (t == 0){
                float4 va = sA[0][0];
                float4 vr = TWO ? sR[0][0] : va;
                float4 o;
                o.x = 0.0f;                 // y_L[0] = 0 by definition
                step(va.y, vr.y); o.y = z;
                step(va.z, vr.z); o.z = z;
                step(va.w, vr.w); o.w = z;
                zt[0] = o;
                g0 = 1;
            }
            #pragma unroll 8
            for (int g = g0; g < TILE_V4; ++g){
                float4 va = sA[cur][g];
                float4 vr = TWO ? sR[cur][g] : va;
                float4 o;
                step(va.x, vr.x); o.x = z;
                step(va.y, vr.y); o.y = z;
                step(va.z, vr.z); o.z = z;
                step(va.w, vr.w); o.w = z;
                zt[g] = o;
            }
        }
        __syncthreads();
    }
}

// Post-pass: y_L = clip(s*z, -96, inf); y = x * 10^(-y_L/20) * mk; scrub.
__global__ __launch_bounds__(256) void drc_post(const float* __restrict__ x, const float* __restrict__ P,
                         float* __restrict__ out, int nvpb, int total_vec){
    int stride = gridDim.x * blockDim.x;
    const float K = 0.16609640474436813f;  // log2(10)/20
    for (int v = blockIdx.x * blockDim.x + threadIdx.x; v < total_vec; v += stride){
        int b = v / nvpb;
        BatchParams bp = load_params(P, b);
        float4 zv = reinterpret_cast<float4*>(out)[v];
        float4 xv = reinterpret_cast<const float4*>(x)[v];
        float4 o;
        #define APPLY(c) { \
            float yl = fmaxf(bp.s * zv.c, -96.0f); \
            float g  = exp2f(-yl * K) * bp.mk; \
            float y  = xv.c * g; \
            o.c = isfinite(y) ? y : 0.0f; }
        APPLY(x) APPLY(y) APPLY(z) APPLY(w)
        #undef APPLY
        reinterpret_cast<float4*>(out)[v] = o;
    }
}

extern "C" void kernel_launch(void* const* d_in, const int* in_sizes, int n_in,
                              void* d_out, int out_size, void* d_ws, size_t ws_size,
                              hipStream_t stream){
    const float* x = (const float*)d_in[0];
    const float* P = (const float*)d_in[1];
    float* out = (float*)d_out;
    float* ws  = (float*)d_ws;

    const int B = in_sizes[1] / 6;
    const int N = in_sizes[0] / B;
    const int nvpb = N / 4;
    const int total_vec = B * nvpb;

    const bool two = (ws_size >= (size_t)in_sizes[0] * sizeof(float));

    const int thr = 256;
    const int blocks = 2048;

    if (two){
        drc_pre<1><<<blocks, thr, 0, stream>>>(x, P, out, ws, nvpb, total_vec);
        drc_scan<1><<<B, 320, 0, stream>>>(out, ws, P, nvpb);
    } else {
        drc_pre<0><<<blocks, thr, 0, stream>>>(x, P, out, nullptr, nvpb, total_vec);
        drc_scan<0><<<B, 320, 0, stream>>>(out, nullptr, P, nvpb);
    }
    drc_post<<<blocks, thr, 0, stream>>>(x, P, out, nvpb, total_vec);
}

// Round 4
// 1561.011 us; speedup vs baseline: 4.0185x; 4.0185x over previous
//
#include <hip/hip_runtime.h>
#include <math.h>

// DRC via exact max-affine scan parallelization.
// Step: z = max(aA*z + ca_n, aR*z + cr_n)  (max-affine, monotone).
// 63-step composition collapses (slopes commute) to:
//   z' = max_{j=0..63} ( aA^j * aR^(63-j) * z + M_j )
// where M_j = max intercept over sequences with j attacks, computed by the DP
//   M_j <- max(aA*M_{j-1} + ca, aR*M_j + cr)   (exact, not speculative).
// passA: per-block DP (parallel). chain: 1 wave/batch, 1 iter per 63 samples.
// pass3: per-block serial replay from exact entries, fused with output gain.

#define SRATE 44100.0f
#define KSTEP 63
#define TILE  128   // blocks per LDS tile in chain kernel

static __device__ __forceinline__ float san(float p){
    p = isnan(p) ? 0.0f : p;
    p = (p == 0.0f) ? 1e-10f : p;
    return p;
}

struct Consts {
    float thr, invr, knee, i2k;   // static curve
    float aA, aR, kAs, kRs, s;    // smoother (z = s*y space)
    float mk;                     // makeup linear gain
    float LA, LR;                 // log2(aA), log2(aR) (exact analytic form)
};

static __device__ __forceinline__ Consts get_consts(const float* __restrict__ P, int b){
    float p0 = san(P[b*6+0]);
    float p1 = san(P[b*6+1]);
    float p2 = san(P[b*6+2]);
    float p3 = san(P[b*6+3]);
    float p4 = san(P[b*6+4]);
    float p5 = san(P[b*6+5]);
    Consts c;
    c.thr  = -p0 * 60.0f;
    float ratio = p1 * 10.0f;
    c.invr = 1.0f / ratio;
    float atk = fmaxf(p2 / 10.0f, 1e-4f);
    float rel = fmaxf(p3 * 3.0f, 0.005f);
    c.knee = p4 * 24.0f;
    c.i2k  = 1.0f / (2.0f * c.knee);
    const float LOG9 = 2.1972245773362196f;
    const float INVLN2 = 1.4426950408889634f;
    c.aA = expf(-LOG9 / (SRATE * atk));
    c.aR = expf(-LOG9 / (SRATE * rel));
    c.LA = (-LOG9 / (SRATE * atk)) * INVLN2;   // log2(aA) computed exactly
    c.LR = (-LOG9 / (SRATE * rel)) * INVLN2;
    c.s  = (c.aA <= c.aR) ? 1.0f : -1.0f;
    c.kAs = c.s * (1.0f - c.aA);
    c.kRs = c.s * (1.0f - c.aR);
    c.mk = exp2f((p5 * 20.0f) * 0.16609640474436813f);  // 10^(mk_dB/20)
    return c;
}

static __device__ __forceinline__ float compute_xl(float xin, const Consts& c){
    float ax = fabsf(xin) + 1e-8f;
    float xg = fmaxf(20.0f * log10f(ax), -96.0f);
    float d  = xg - c.thr;
    float t2 = d + d;
    float u  = (d + c.knee) * 0.5f;
    float yk = xg + (c.invr * (u * u)) * c.i2k;
    float ya = c.thr + d * c.invr;
    float yg = (t2 < -c.knee) ? xg : ((t2 > c.knee) ? ya : yk);
    return xg - yg;
}

template<int CTRL>
static __device__ __forceinline__ float maxdpp(float v){
    int t = __builtin_amdgcn_update_dpp(__float_as_int(v), __float_as_int(v),
                                        CTRL, 0xF, 0xF, false);
    return fmaxf(v, __int_as_float(t));
}

// ---------------- passA: per-block DP over 63 steps ----------------
// Block b covers step samples n in [2 + 63b, 2 + 63b + t). Lane j holds M_j.
__global__ __launch_bounds__(256) void drc_passA(
    const float* __restrict__ x, const float* __restrict__ P,
    float* __restrict__ Mmain, float* __restrict__ Mlast,
    int N, int NBLK, int tailSteps)
{
    const int lane = threadIdx.x & 63;
    const int gw = blockIdx.x * (blockDim.x >> 6) + (threadIdx.x >> 6);
    const int batch = blockIdx.y;
    if (gw >= NBLK) return;
    Consts c = get_consts(P, batch);
    const int t = (gw == NBLK - 1) ? tailSteps : KSTEP;

    const size_t base = (size_t)batch * N;
    int n = 2 + KSTEP * gw + lane;
    if (n > N - 1) n = N - 1;                 // lane 63 (and tail) guard
    float xl = compute_xl(x[base + n], c);

    float M = (lane == 0) ? 0.0f : -1e38f;
    #pragma unroll
    for (int i = 0; i < KSTEP; ++i){
        if (i < t){
            float xli = __int_as_float(__builtin_amdgcn_readlane(__float_as_int(xl), i));
            float ca = c.kAs * xli;
            float cr = c.kRs * xli;
            float Mp = __shfl_up(M, 1, 64);
            if (lane == 0) Mp = -1e38f;
            M = fmaxf(fmaf(c.aA, Mp, ca), fmaf(c.aR, M, cr));
        }
    }
    if (lane < KSTEP)
        Mmain[((size_t)batch * NBLK + gw) * KSTEP + lane] = M;
    else
        Mlast[(size_t)batch * NBLK + gw] = M;
}

// ---------------- chain: 1 block per batch, 1 iter per 63 samples ----------------
__global__ __launch_bounds__(192) void drc_chain(
    const float* __restrict__ x, const float* __restrict__ P,
    const float* __restrict__ Mmain, const float* __restrict__ Mlast,
    float* __restrict__ entries, int N, int NBLK, int tailSteps)
{
    const int batch = blockIdx.x;
    const int tid = threadIdx.x;
    const int lane = tid & 63;
    const int w = tid >> 6;
    Consts c = get_consts(P, batch);

    __shared__ float sM[2][TILE * 64];

    const float* gM = Mmain + (size_t)batch * NBLK * KSTEP;
    const float* gL = Mlast + (size_t)batch * NBLK;
    float* ent = entries + (size_t)batch * NBLK;

    // slopes s_l = aA^l * aR^(63-l), exact-exponent form
    float sl  = exp2f((float)lane * c.LA + (float)(KSTEP - lane) * c.LR);
    float slT = (lane <= tailSteps)
              ? exp2f((float)lane * c.LA + (float)(tailSteps - lane) * c.LR)
              : 0.0f;

    // prologue: one serial step for sample 1 (y0 = 0 by definition)
    float xl1 = compute_xl(x[(size_t)batch * N + 1], c);
    float z = fmaxf(c.kAs * xl1, c.kRs * xl1);   // y_1 in z-space

    const int ntiles = (NBLK + TILE - 1) / TILE;

    auto stage = [&](int tile, int buf){
        const int s = tid - 64;                  // 0..127
        const int b0 = tile * TILE;
        const int cnt = min(TILE, NBLK - b0);
        for (int f = s; f < cnt * KSTEP; f += 128){
            unsigned b = (unsigned)f / KSTEP;
            unsigned j = (unsigned)f - b * KSTEP;
            sM[buf][b * 64 + j] = gM[(size_t)b0 * KSTEP + f];
        }
        if (s < cnt) sM[buf][s * 64 + 63] = gL[b0 + s];
    };

    if (w > 0) stage(0, 0);
    __syncthreads();

    float eacc = 0.0f;
    int ebase = 0;

    for (int tile = 0; tile < ntiles; ++tile){
        const int buf = tile & 1;
        if (w > 0){
            if (tile + 1 < ntiles) stage(tile + 1, buf ^ 1);
        } else {
            const int b0 = tile * TILE;
            const int cnt = min(TILE, NBLK - b0);
            // 2-deep LDS prefetch so ds_read latency is off the chain
            float m0 = sM[buf][lane];
            float m1 = sM[buf][(size_t)min(1, cnt - 1) * 64 + lane];
            for (int it = 0; it < cnt; ++it){
                const int b = b0 + it;
                float mn = sM[buf][(size_t)min(it + 2, cnt - 1) * 64 + lane];
                // record entry[b] = z before applying block b
                // (z is wave-uniform; predicated assign == writelane)
                if (lane == (b & 63)) eacc = z;
                float slope = (b == NBLK - 1) ? slT : sl;
                float tv = fmaf(slope, z, m0);
                tv = maxdpp<0xB1>(tv);    // quad_perm [1,0,3,2]  xor1
                tv = maxdpp<0x4E>(tv);    // quad_perm [2,3,0,1]  xor2
                tv = maxdpp<0x141>(tv);   // row_half_mirror      xor4
                tv = maxdpp<0x140>(tv);   // row_mirror           xor8
                tv = maxdpp<0x142>(tv);   // row_bcast15 (merge rows up)
                tv = maxdpp<0x143>(tv);   // row_bcast31 (lane 63 = full max)
                z = __int_as_float(__builtin_amdgcn_readlane(__float_as_int(tv), 63));
                if ((b & 63) == 63){ ent[ebase + lane] = eacc; ebase += 64; }
                m0 = m1; m1 = mn;
            }
        }
        __syncthreads();
    }
    if (w == 0){
        const int rem = NBLK - ebase;
        if (rem > 0 && lane < rem) ent[ebase + lane] = eacc;
    }
}

// ---------------- pass3: replay each block from exact entry, fused output ----------------
__global__ __launch_bounds__(256) void drc_pass3(
    const float* __restrict__ x, const float* __restrict__ P,
    const float* __restrict__ entries, float* __restrict__ out,
    int N, int NBLK, int tailSteps, int B)
{
    const int gid = blockIdx.x * blockDim.x + threadIdx.x;
    const int batch = gid / NBLK;
    if (batch >= B) return;
    const int b = gid - batch * NBLK;
    Consts c = get_consts(P, batch);
    const float KL = 0.16609640474436813f;   // log2(10)/20
    const size_t base = (size_t)batch * N;

    float z = entries[(size_t)batch * NBLK + b];
    if (b == 0){
        float x0 = x[base + 0];
        float y0 = x0 * c.mk;                 // y_L[0] = 0 -> gain 1
        out[base + 0] = isfinite(y0) ? y0 : 0.0f;
        float x1 = x[base + 1];
        float yl1 = fmaxf(c.s * z, -96.0f);   // entry[0] == y_1 (z-space)
        float y1 = x1 * (exp2f(-yl1 * KL) * c.mk);
        out[base + 1] = isfinite(y1) ? y1 : 0.0f;
    }
    const int t = (b == NBLK - 1) ? tailSteps : KSTEP;
    const int n0 = 2 + b * KSTEP;
    for (int i = 0; i < t; ++i){
        const int n = n0 + i;
        float xv = x[base + n];
        float xl = compute_xl(xv, c);
        z = fmaxf(fmaf(c.aA, z, c.kAs * xl), fmaf(c.aR, z, c.kRs * xl));
        float yl = fmaxf(c.s * z, -96.0f);
        float y = xv * (exp2f(-yl * KL) * c.mk);
        out[base + n] = isfinite(y) ? y : 0.0f;
    }
}

extern "C" void kernel_launch(void* const* d_in, const int* in_sizes, int n_in,
                              void* d_out, int out_size, void* d_ws, size_t ws_size,
                              hipStream_t stream){
    const float* x = (const float*)d_in[0];
    const float* P = (const float*)d_in[1];
    float* out = (float*)d_out;
    float* ws  = (float*)d_ws;

    const int B = in_sizes[1] / 6;
    const int N = in_sizes[0] / B;

    // blocks of 63 steps over samples 2..N-1 (sample 1 is the chain prologue)
    const int NBLK = (N - 2 + KSTEP - 1) / KSTEP;
    const int tailSteps = (N - 2) - (NBLK - 1) * KSTEP;

    float* Mmain   = out;                 // 63 floats per block (fits out exactly)
    float* entries = ws;                  // B*NBLK floats
    float* Mlast   = ws + (size_t)B * NBLK;

    {
        dim3 g((NBLK + 3) / 4, B);
        drc_passA<<<g, 256, 0, stream>>>(x, P, Mmain, Mlast, N, NBLK, tailSteps);
    }
    drc_chain<<<B, 192, 0, stream>>>(x, P, Mmain, Mlast, entries, N, NBLK, tailSteps);
    {
        int total = B * NBLK;
        drc_pass3<<<(total + 255) / 256, 256, 0, stream>>>(x, P, entries, out,
                                                           N, NBLK, tailSteps, B);
    }
}

// Round 5
// 584.527 us; speedup vs baseline: 10.7315x; 2.6706x over previous
//
#include <hip/hip_runtime.h>
#include <math.h>

// DRC via exact max-affine scan parallelization, 255-step blocks.
// Step: z = max(aA*z + ca_n, aR*z + cr_n) (max-affine, monotone). A k-step
// composition has only k+1 slopes aA^j aR^(k-j); intercepts M_j obey the DP
//   M'_j = max(aA*M_{j-1} + ca, aR*M_j + cr)   (exact).
// KSTEP=255 -> 256 intercepts = 4 per lane (blocked: lane l holds j=4l..4l+3).
// passA: per-block DP (throughput-parallel). chain: 1 wave/batch, one
// 64-lane max-affine application per 255 samples, staging waves batch-load
// M tiles into LDS. pass3: per-block serial replay from exact entries.

#define SRATE 44100.0f
#define KSTEP 255
#define INTC  256
#define TILE2 32
#define NEG_INF -1e38f

static __device__ __forceinline__ float san(float p){
    p = isnan(p) ? 0.0f : p;
    p = (p == 0.0f) ? 1e-10f : p;
    return p;
}

struct Consts {
    float thr, invr, knee, i2k;
    float aA, aR, kAs, kRs, s;
    float mk;
    float LA, LR;    // log2(aA), log2(aR), exact analytic form
};

static __device__ __forceinline__ Consts get_consts(const float* __restrict__ P, int b){
    float p0 = san(P[b*6+0]);
    float p1 = san(P[b*6+1]);
    float p2 = san(P[b*6+2]);
    float p3 = san(P[b*6+3]);
    float p4 = san(P[b*6+4]);
    float p5 = san(P[b*6+5]);
    Consts c;
    c.thr  = -p0 * 60.0f;
    float ratio = p1 * 10.0f;
    c.invr = 1.0f / ratio;
    float atk = fmaxf(p2 / 10.0f, 1e-4f);
    float rel = fmaxf(p3 * 3.0f, 0.005f);
    c.knee = p4 * 24.0f;
    c.i2k  = 1.0f / (2.0f * c.knee);
    const float LOG9 = 2.1972245773362196f;
    const float INVLN2 = 1.4426950408889634f;
    c.aA = expf(-LOG9 / (SRATE * atk));
    c.aR = expf(-LOG9 / (SRATE * rel));
    c.LA = (-LOG9 / (SRATE * atk)) * INVLN2;
    c.LR = (-LOG9 / (SRATE * rel)) * INVLN2;
    c.s  = (c.aA <= c.aR) ? 1.0f : -1.0f;
    c.kAs = c.s * (1.0f - c.aA);
    c.kRs = c.s * (1.0f - c.aR);
    c.mk = exp2f((p5 * 20.0f) * 0.16609640474436813f);
    return c;
}

static __device__ __forceinline__ float compute_xl(float xin, const Consts& c){
    float ax = fabsf(xin) + 1e-8f;
    float xg = fmaxf(20.0f * log10f(ax), -96.0f);
    float d  = xg - c.thr;
    float t2 = d + d;
    float u  = (d + c.knee) * 0.5f;
    float yk = xg + (c.invr * (u * u)) * c.i2k;
    float ya = c.thr + d * c.invr;
    float yg = (t2 < -c.knee) ? xg : ((t2 > c.knee) ? ya : yk);
    return xg - yg;
}

template<int CTRL>
static __device__ __forceinline__ float maxdpp(float v){
    int t = __builtin_amdgcn_update_dpp(__float_as_int(v), __float_as_int(v),
                                        CTRL, 0xF, 0xF, false);
    return fmaxf(v, __int_as_float(t));
}

static __device__ __forceinline__ float rdlane(float v, int l){
    return __int_as_float(__builtin_amdgcn_readlane(__float_as_int(v), l));
}

// one DP step over new sample xli (updates M0..M3 in reverse so old values
// are consumed; p3 = old M3 from lane-1 = old M_{4l-1})
#define STEPA(xli) { \
    float ca = c.kAs * (xli); \
    float cr = c.kRs * (xli); \
    float p3 = __shfl_up(M3, 1, 64); \
    p3 = (lane == 0) ? NEG_INF : p3; \
    M3 = fmaxf(fmaf(c.aA, M2, ca), fmaf(c.aR, M3, cr)); \
    M2 = fmaxf(fmaf(c.aA, M1, ca), fmaf(c.aR, M2, cr)); \
    M1 = fmaxf(fmaf(c.aA, M0, ca), fmaf(c.aR, M1, cr)); \
    M0 = fmaxf(fmaf(c.aA, p3, ca), fmaf(c.aR, M0, cr)); \
}

// ---------------- passA: per-block 255-step DP ----------------
__global__ __launch_bounds__(256) void drc_passA(
    const float* __restrict__ x, const float* __restrict__ P,
    float* __restrict__ Mout, float* __restrict__ Movf,
    int N, int NBLK, int tailSteps, unsigned CAP4)
{
    const int lane = threadIdx.x & 63;
    const int gw = blockIdx.x * 4 + (threadIdx.x >> 6);
    const int batch = blockIdx.y;
    if (gw >= NBLK) return;
    Consts c = get_consts(P, batch);
    const int t = (gw == NBLK - 1) ? tailSteps : KSTEP;
    const size_t base = (size_t)batch * N;
    const int n0 = 2 + KSTEP * gw;

    const int i0 = n0 + 4 * lane;
    float xl0 = compute_xl(x[base + min(i0 + 0, N - 1)], c);
    float xl1 = compute_xl(x[base + min(i0 + 1, N - 1)], c);
    float xl2 = compute_xl(x[base + min(i0 + 2, N - 1)], c);
    float xl3 = compute_xl(x[base + min(i0 + 3, N - 1)], c);

    float M0 = (lane == 0) ? 0.0f : NEG_INF;
    float M1 = NEG_INF, M2 = NEG_INF, M3 = NEG_INF;

    if (t == KSTEP){
        for (int g = 0; g < 64; ++g){
            float xa0 = rdlane(xl0, g);
            float xa1 = rdlane(xl1, g);
            float xa2 = rdlane(xl2, g);
            float xa3 = rdlane(xl3, g);
            STEPA(xa0);
            STEPA(xa1);
            STEPA(xa2);
            if (g < 63) { STEPA(xa3); }   // 255 = 63*4 + 3
        }
    } else {
        for (int g = 0; g < 64; ++g){
            int ib = 4 * g;
            if (ib >= t) break;
            float xa0 = rdlane(xl0, g);
            float xa1 = rdlane(xl1, g);
            float xa2 = rdlane(xl2, g);
            float xa3 = rdlane(xl3, g);
            if (ib + 0 < t) { STEPA(xa0); }
            if (ib + 1 < t) { STEPA(xa1); }
            if (ib + 2 < t) { STEPA(xa2); }
            if (ib + 3 < t) { STEPA(xa3); }
        }
    }

    const size_t f4 = ((size_t)batch * NBLK + gw) * 64 + lane;
    float4 v = { M0, M1, M2, M3 };
    if (f4 < CAP4) ((float4*)Mout)[f4] = v;
    else           ((float4*)Movf)[f4 - CAP4] = v;
}

// ---------------- chain: 1 block per batch ----------------
__global__ __launch_bounds__(192) void drc_chain(
    const float* __restrict__ x, const float* __restrict__ P,
    const float* __restrict__ Mout, const float* __restrict__ Movf,
    float* __restrict__ entries, int N, int NBLK, unsigned CAP4)
{
    const int batch = blockIdx.x;
    const int tid = threadIdx.x;
    const int lane = tid & 63;
    const int w = tid >> 6;
    Consts c = get_consts(P, batch);

    __shared__ float sM[2][TILE2 * INTC];   // 64 KiB

    const float4* outM4 = (const float4*)Mout;
    const float4* ovf4  = (const float4*)Movf;
    float* ent = entries + (size_t)batch * NBLK;

    // slopes for a full 255-step block: j = 4*lane + e
    const float j0 = (float)(4 * lane);
    float sl0 = exp2f((j0 + 0.0f) * c.LA + (float)(KSTEP - 4*lane - 0) * c.LR);
    float sl1 = exp2f((j0 + 1.0f) * c.LA + (float)(KSTEP - 4*lane - 1) * c.LR);
    float sl2 = exp2f((j0 + 2.0f) * c.LA + (float)(KSTEP - 4*lane - 2) * c.LR);
    float sl3 = exp2f((j0 + 3.0f) * c.LA + (float)(KSTEP - 4*lane - 3) * c.LR);

    // prologue: sample 1 from y0 = 0
    float xl1 = compute_xl(x[(size_t)batch * N + 1], c);
    float z = fmaxf(c.kAs * xl1, c.kRs * xl1);

    const int NMAIN = NBLK - 1;              // tail block peeled (pass3 replays it)
    const int ntiles = (NMAIN + TILE2 - 1) / TILE2;

    auto loadM4 = [&](size_t f4) -> float4 {
        return (f4 < CAP4) ? outM4[f4] : ovf4[f4 - CAP4];
    };

    auto stage = [&](int tile, int buf){
        const int s = tid - 64;              // 0..127
        const int b0 = tile * TILE2;
        const int cnt = min(TILE2, NMAIN - b0);
        const int total4 = cnt * 64;
        const size_t fb = ((size_t)batch * NBLK + b0) * 64;
        float4* dst = (float4*)&sM[buf][0];
        if (total4 == TILE2 * 64){
            float4 tmp[16];
            #pragma unroll
            for (int k = 0; k < 16; ++k) tmp[k] = loadM4(fb + (size_t)k * 128 + s);
            #pragma unroll
            for (int k = 0; k < 16; ++k) dst[k * 128 + s] = tmp[k];
        } else {
            for (int q = s; q < total4; q += 128) dst[q] = loadM4(fb + q);
        }
    };

    if (w > 0 && ntiles > 0) stage(0, 0);
    __syncthreads();

    float eacc = 0.0f;
    int ebase = 0;

    for (int tile = 0; tile < ntiles; ++tile){
        const int buf = tile & 1;
        if (w > 0){
            if (tile + 1 < ntiles) stage(tile + 1, buf ^ 1);
        } else {
            const int b0 = tile * TILE2;
            const int cnt = min(TILE2, NMAIN - b0);
            const float4* sb4 = (const float4*)&sM[buf][0];
            // 3-deep register prefetch of M rows
            float4 m0 = sb4[lane];
            float4 m1 = sb4[min(1, cnt - 1) * 64 + lane];
            float4 m2 = sb4[min(2, cnt - 1) * 64 + lane];
            for (int it = 0; it < cnt; ++it){
                const int b = b0 + it;
                float4 mn = sb4[min(it + 3, cnt - 1) * 64 + lane];
                if (lane == (b & 63)) eacc = z;     // entry BEFORE block b
                float f0 = fmaf(sl0, z, m0.x);
                float f1 = fmaf(sl1, z, m0.y);
                float f2 = fmaf(sl2, z, m0.z);
                float f3 = fmaf(sl3, z, m0.w);
                float tv = fmaxf(fmaxf(f0, f1), fmaxf(f2, f3));
                tv = maxdpp<0xB1>(tv);    // quad_perm xor1
                tv = maxdpp<0x4E>(tv);    // quad_perm xor2
                tv = maxdpp<0x141>(tv);   // row_half_mirror
                tv = maxdpp<0x140>(tv);   // row_mirror
                tv = maxdpp<0x142>(tv);   // row_bcast15
                tv = maxdpp<0x143>(tv);   // row_bcast31 -> lane 63 = full max
                z = rdlane(tv, 63);
                if ((b & 63) == 63){ ent[ebase + lane] = eacc; ebase += 64; }
                m0 = m1; m1 = m2; m2 = mn;
            }
        }
        __syncthreads();
    }

    if (w == 0){
        const int bT = NBLK - 1;
        if (lane == (bT & 63)) eacc = z;         // entry for peeled tail block
        const int rem = NBLK - ebase;
        if (lane < rem) ent[ebase + lane] = eacc;
    }
}

// ---------------- pass3: replay each block from exact entry, fused output ----------------
__global__ __launch_bounds__(256) void drc_pass3(
    const float* __restrict__ x, const float* __restrict__ P,
    const float* __restrict__ entries, float* __restrict__ out,
    int N, int NBLK, int tailSteps, int B)
{
    const int gid = blockIdx.x * blockDim.x + threadIdx.x;
    const int batch = gid / NBLK;
    if (batch >= B) return;
    const int b = gid - batch * NBLK;
    Consts c = get_consts(P, batch);
    const float KL = 0.16609640474436813f;   // log2(10)/20
    const size_t base = (size_t)batch * N;

    float z = entries[(size_t)batch * NBLK + b];
    if (b == 0){
        float x0 = x[base + 0];
        float y0 = x0 * c.mk;                 // y_L[0] = 0 -> gain 1
        out[base + 0] = isfinite(y0) ? y0 : 0.0f;
        float x1 = x[base + 1];
        float yl1 = fmaxf(c.s * z, -96.0f);   // entry[0] == y_1 (z-space)
        float y1 = x1 * (exp2f(-yl1 * KL) * c.mk);
        out[base + 1] = isfinite(y1) ? y1 : 0.0f;
    }
    const int t = (b == NBLK - 1) ? tailSteps : KSTEP;
    const int n0 = 2 + b * KSTEP;

    #define P3STEP(xv) { \
        float xl = compute_xl(xv, c); \
        z = fmaxf(fmaf(c.aA, z, c.kAs * xl), fmaf(c.aR, z, c.kRs * xl)); }
    #define P3OUT(xv, dst) { \
        float yl = fmaxf(c.s * z, -96.0f); \
        float y = (xv) * (exp2f(-yl * KL) * c.mk); \
        dst = isfinite(y) ? y : 0.0f; }

    int i = 0;
    for (; i + 4 <= t; i += 4){
        const size_t n = base + n0 + i;
        float a0 = x[n + 0];
        float a1 = x[n + 1];
        float a2 = x[n + 2];
        float a3 = x[n + 3];
        float o0, o1, o2, o3;
        P3STEP(a0); P3OUT(a0, o0);
        P3STEP(a1); P3OUT(a1, o1);
        P3STEP(a2); P3OUT(a2, o2);
        P3STEP(a3); P3OUT(a3, o3);
        out[n + 0] = o0; out[n + 1] = o1; out[n + 2] = o2; out[n + 3] = o3;
    }
    for (; i < t; ++i){
        const size_t n = base + n0 + i;
        float a = x[n];
        float o;
        P3STEP(a); P3OUT(a, o);
        out[n] = o;
    }
}

extern "C" void kernel_launch(void* const* d_in, const int* in_sizes, int n_in,
                              void* d_out, int out_size, void* d_ws, size_t ws_size,
                              hipStream_t stream){
    const float* x = (const float*)d_in[0];
    const float* P = (const float*)d_in[1];
    float* out = (float*)d_out;
    float* ws  = (float*)d_ws;

    const int B = in_sizes[1] / 6;
    const int N = in_sizes[0] / B;

    const int NBLK = (N - 2 + KSTEP - 1) / KSTEP;
    const int tailSteps = (N - 2) - (NBLK - 1) * KSTEP;

    const unsigned OUT_CAP = (unsigned)out_size;       // floats available in d_out
    const unsigned CAP4 = OUT_CAP / 4;

    float* entries = ws;
    size_t entN = (((size_t)B * NBLK) + 3) & ~(size_t)3;  // 16B-align overflow
    float* Movf = ws + entN;

    {
        dim3 g((NBLK + 3) / 4, B);
        drc_passA<<<g, 256, 0, stream>>>(x, P, out, Movf, N, NBLK, tailSteps, CAP4);
    }
    drc_chain<<<B, 192, 0, stream>>>(x, P, out, Movf, entries, N, NBLK, CAP4);
    {
        int total = B * NBLK;
        drc_pass3<<<(total + 255) / 256, 256, 0, stream>>>(x, P, entries, out,
                                                           N, NBLK, tailSteps, B);
    }
}